// Round 1
// 764.585 us; speedup vs baseline: 1.0731x; 1.0731x over previous
//
#include <hip/hip_runtime.h>
#include <float.h>

// ---------------- counting-sort + gather-reduce multi-aggregation ----------------
// ws layout (ints): counts[N] | offsets[N+1] | cursor[N] | partials[512] | perm[E]

__global__ void zero_counts(int* __restrict__ counts, int N) {
    int i = blockIdx.x * 256 + threadIdx.x;
    if (i < N) counts[i] = 0;
}

__global__ void hist(const int* __restrict__ dst, int stride, int* __restrict__ counts, int E) {
    int e = blockIdx.x * 256 + threadIdx.x;
    if (e < E) {
        // int64 dst: load the full 8B coalesced, take low word (ids < 2^31)
        int n = (stride == 2) ? (int)((const long long*)dst)[e] : dst[e];
        atomicAdd(&counts[n], 1);
    }
}

// Per-block exclusive scan; writes block-local exclusive values + block totals.
__global__ void scan1(const int* __restrict__ counts, int* __restrict__ offsets,
                      int* __restrict__ partials, int N) {
    __shared__ int s[256];
    int t = threadIdx.x;
    int i = blockIdx.x * 256 + t;
    int x = (i < N) ? counts[i] : 0;
    s[t] = x;
    __syncthreads();
    for (int o = 1; o < 256; o <<= 1) {
        int y = (t >= o) ? s[t - o] : 0;
        __syncthreads();
        s[t] += y;
        __syncthreads();
    }
    if (i < N) offsets[i] = s[t] - x;          // exclusive within block
    if (t == 255) partials[blockIdx.x] = s[255];
}

// Single-block exclusive scan of up to 512 partials.
__global__ void scan2(int* __restrict__ partials, int NB) {
    __shared__ int s[512];
    int t = threadIdx.x;
    int x = (t < NB) ? partials[t] : 0;
    s[t] = x;
    __syncthreads();
    for (int o = 1; o < 512; o <<= 1) {
        int y = (t >= o) ? s[t - o] : 0;
        __syncthreads();
        s[t] += y;
        __syncthreads();
    }
    if (t < NB) partials[t] = s[t] - x;        // exclusive
}

__global__ void scan3(int* __restrict__ offsets, const int* __restrict__ partials,
                      int* __restrict__ cursor, int N, int E) {
    int i = blockIdx.x * 256 + threadIdx.x;
    if (i < N) {
        int off = offsets[i] + partials[blockIdx.x];
        offsets[i] = off;
        cursor[i] = off;
    }
    if (i == 0) offsets[N] = E;
}

__global__ void permscatter(const int* __restrict__ dst, int stride,
                            int* __restrict__ cursor, int* __restrict__ perm, int E) {
    int e = blockIdx.x * 256 + threadIdx.x;
    if (e < E) {
        int n = (stride == 2) ? (int)((const long long*)dst)[e] : dst[e];
        int pos = atomicAdd(&cursor[n], 1);
        perm[pos] = e;
    }
}

// One wave per node; lane = feature. 64-edge chunked eid load (coalesced) +
// shuffle broadcast + 4-wide independent row gathers => 4 outstanding 256B
// loads per wave (vs 1 before): converts latency-bound gather to BW-bound.
__global__ void reduce(const float* __restrict__ msg, const int* __restrict__ perm,
                       const int* __restrict__ offsets, float* __restrict__ out, int N) {
    int node = blockIdx.x * 4 + (threadIdx.x >> 6);
    if (node >= N) return;
    int lane = threadIdx.x & 63;
    int beg = offsets[node];
    int end = offsets[node + 1];

    float s0 = 0.f, s1 = 0.f, s2 = 0.f, s3 = 0.f;
    float q0 = 0.f, q1 = 0.f, q2 = 0.f, q3 = 0.f;
    float m0 = -FLT_MAX, m1 = -FLT_MAX, m2 = -FLT_MAX, m3 = -FLT_MAX;

    const float* mp = msg + lane;

    for (int base = beg; base < end; base += 64) {
        int cnt = end - base;
        if (cnt > 64) cnt = 64;
        // one coalesced 256B load serves up to 64 iterations of eids
        int idx = base + lane;
        if (idx >= end) idx = end - 1;          // clamp: safe, wave-uniform loop bound
        int eid_l = perm[idx];

        int j = 0;
        for (; j + 4 <= cnt; j += 4) {
            int e0 = __shfl(eid_l, j + 0);
            int e1 = __shfl(eid_l, j + 1);
            int e2 = __shfl(eid_l, j + 2);
            int e3 = __shfl(eid_l, j + 3);
            float v0 = mp[(long long)e0 << 6];  // 4 independent 256B row loads in flight
            float v1 = mp[(long long)e1 << 6];
            float v2 = mp[(long long)e2 << 6];
            float v3 = mp[(long long)e3 << 6];
            s0 += v0; q0 += v0 * v0; m0 = fmaxf(m0, v0);
            s1 += v1; q1 += v1 * v1; m1 = fmaxf(m1, v1);
            s2 += v2; q2 += v2 * v2; m2 = fmaxf(m2, v2);
            s3 += v3; q3 += v3 * v3; m3 = fmaxf(m3, v3);
        }
        for (; j < cnt; ++j) {
            int e = __shfl(eid_l, j);
            float v = mp[(long long)e << 6];
            s0 += v; q0 += v * v; m0 = fmaxf(m0, v);
        }
    }

    float s  = (s0 + s1) + (s2 + s3);
    float sq = (q0 + q1) + (q2 + q3);
    float mx = fmaxf(fmaxf(m0, m1), fmaxf(m2, m3));

    float deg  = fmaxf((float)(end - beg), 1.0f);
    float mean = s / deg;
    float var  = fmaxf(sq / deg - mean * mean, 0.0f);
    float mxo  = (end > beg) ? mx : 0.0f;       // empty segment -> 0 (matches isfinite replace)

    float* base_out = out + (long long)node * 256;
    base_out[lane]       = s;
    base_out[64 + lane]  = mean;
    base_out[128 + lane] = mxo;
    base_out[192 + lane] = sqrtf(var + 1e-8f);
}

extern "C" void kernel_launch(void* const* d_in, const int* in_sizes, int n_in,
                              void* d_out, int out_size, void* d_ws, size_t ws_size,
                              hipStream_t stream) {
    const float* msg = (const float*)d_in[0];
    const int*   dst = (const int*)d_in[1];
    float* out = (float*)d_out;

    int E = in_sizes[0] / 64;                 // 1,600,000
    int N = out_size / 256;                   // 100,000
    int stride = (in_sizes[1] == 2 * E) ? 2 : 1;   // int64-as-int32-pairs defense

    int* counts   = (int*)d_ws;
    int* offsets  = counts + N;               // N+1
    int* cursor   = offsets + N + 1;
    int* partials = cursor + N;               // 512
    int* perm     = partials + 512;           // E

    int NB_N = (N + 255) / 256;               // 391 (<= 512 required for scan2)
    int NB_E = (E + 255) / 256;

    zero_counts<<<NB_N, 256, 0, stream>>>(counts, N);
    hist<<<NB_E, 256, 0, stream>>>(dst, stride, counts, E);
    scan1<<<NB_N, 256, 0, stream>>>(counts, offsets, partials, N);
    scan2<<<1, 512, 0, stream>>>(partials, NB_N);
    scan3<<<NB_N, 256, 0, stream>>>(offsets, partials, cursor, N, E);
    permscatter<<<NB_E, 256, 0, stream>>>(dst, stride, cursor, perm, E);
    reduce<<<(N + 3) / 4, 256, 0, stream>>>(msg, perm, offsets, out, N);
}